// Round 12
// baseline (132.471 us; speedup 1.0000x reference)
//
#include <hip/hip_runtime.h>
#include <hip/hip_bf16.h>
#include <cstdint>

typedef __bf16 bf16_t;
typedef __bf16 bf16x8 __attribute__((ext_vector_type(8)));
typedef __bf16 bf16x4 __attribute__((ext_vector_type(4)));
typedef __bf16 bf16x2 __attribute__((ext_vector_type(2)));
typedef float  f32x4  __attribute__((ext_vector_type(4)));
typedef float  f32x16 __attribute__((ext_vector_type(16)));
typedef unsigned uint4v __attribute__((ext_vector_type(4)));

#define AS1 __attribute__((address_space(1)))
#define AS3 __attribute__((address_space(3)))

static __device__ __forceinline__ void gld_lds16(const void* g, void* l) {
  __builtin_amdgcn_global_load_lds((AS1 void*)g, (AS3 void*)l, 16, 0, 0);
}

// truncation-pack two f32 -> bf16x2 word via one v_perm_b32 (lo=a, hi=b).
// Bias cancels in O = sum(pV)/sum(p) since ls uses the same truncated P.
static __device__ __forceinline__ unsigned pk2t(float a, float b) {
  return __builtin_amdgcn_perm(__builtin_bit_cast(unsigned, a),
                               __builtin_bit_cast(unsigned, b), 0x03020706u);
}

// ---------------- convert / transpose ----------------

__global__ __launch_bounds__(256) void convert_f32_bf16(const float* __restrict__ in,
                                                        bf16_t* __restrict__ out, int n4) {
  int i = blockIdx.x * 256 + threadIdx.x;
  if (i < n4) {
    float4 v = ((const float4*)in)[i];
    bf16x4 o;
    o[0] = (bf16_t)v.x; o[1] = (bf16_t)v.y; o[2] = (bf16_t)v.z; o[3] = (bf16_t)v.w;
    *(bf16x4*)(out + (size_t)i * 4) = o;
  }
}

__global__ __launch_bounds__(256) void transpose_w(const float* __restrict__ in,
                                                   bf16_t* __restrict__ out, int K, int N) {
  __shared__ float tile[32][33];
  const int t = threadIdx.x, c = t & 31, r0 = t >> 5;
  const int bx = blockIdx.x, by = blockIdx.y;
#pragma unroll
  for (int i = 0; i < 4; ++i) {
    int r = r0 + i * 8;
    tile[r][c] = in[(size_t)(by * 32 + r) * N + bx * 32 + c];
  }
  __syncthreads();
#pragma unroll
  for (int i = 0; i < 4; ++i) {
    int r = r0 + i * 8;
    out[(size_t)(bx * 32 + r) * K + by * 32 + c] = (bf16_t)tile[c][r];
  }
}

// V row-major [32][2048][64] -> Vt [32][64][2048] with quad-permuted kv
// (perm within each 32-kv block: q3=kv>>2&7 -> dq swaps q3's low 2 bits).
// 32x32 u16 tiles, pad 34 (write 2-way/free, read 17c+r/2 distinct), both
// global sides coalesced (write covers permuted-within-64B lines).
__global__ __launch_bounds__(256) void transpose_v(const bf16_t* __restrict__ in,
                                                   bf16_t* __restrict__ out) {
  __shared__ unsigned short tile[32][34];
  const int t = threadIdx.x, c = t & 31, r0 = t >> 5;
  const int dt = blockIdx.x;   // d block  (0..1)
  const int kt = blockIdx.y;   // kv block (0..63)
  const int bh = blockIdx.z;   // 0..31
  const unsigned short* src =
      (const unsigned short*)(in + ((size_t)bh * 2048 + kt * 32) * 64 + dt * 32);
#pragma unroll
  for (int i = 0; i < 4; ++i) {
    const int r = r0 + i * 8;                    // kv-local
    tile[r][c] = src[(size_t)r * 64 + c];        // c = d-local
  }
  __syncthreads();
  unsigned short* dst =
      (unsigned short*)(out + ((size_t)bh * 64 + dt * 32) * 2048 + kt * 32);
  const int q3 = c >> 2;
  const int dq = (q3 & 4) | ((q3 & 1) << 1) | ((q3 >> 1) & 1);
  const int cp = (dq << 2) | (c & 3);            // permuted kv-local
#pragma unroll
  for (int i = 0; i < 4; ++i) {
    const int r = r0 + i * 8;                    // d-local
    dst[(size_t)r * 2048 + cp] = tile[c][r];
  }
}

// ---------------- 128x128 bf16 GEMM core ----------------
template <int KDIM>
static __device__ __forceinline__ void gemm128_compute(const bf16_t* __restrict__ A,
                                                       const bf16_t* __restrict__ Bt,
                                                       bf16_t* lA, bf16_t* lB,
                                                       f32x4 acc[4][4],
                                                       int bm, int bn) {
  const int t = threadIdx.x;
  const int lr = t & 15, g = (t >> 4) & 3;
  const int w = t >> 6, wr = w >> 1, wc = w & 1;

  for (int kt = 0; kt < KDIM; kt += 32) {
    __syncthreads();
#pragma unroll
    for (int c2 = 0; c2 < 2; ++c2) {
      const int idx = c2 * 256 + t;
      const int row = idx >> 2, cb = idx & 3;
      const int ldsoff = ((t & 192) + c2 * 256) * 8;
      gld_lds16(A  + (size_t)(bm * 128 + row) * KDIM + kt + cb * 8, lA + ldsoff);
      gld_lds16(Bt + (size_t)(bn * 128 + row) * KDIM + kt + cb * 8, lB + ldsoff);
    }
    __syncthreads();
    bf16x8 af[4], bv[4];
#pragma unroll
    for (int mi = 0; mi < 4; ++mi)
      af[mi] = *(const bf16x8*)(lA + (wr * 64 + mi * 16 + lr) * 32 + g * 8);
#pragma unroll
    for (int ni = 0; ni < 4; ++ni)
      bv[ni] = *(const bf16x8*)(lB + (wc * 64 + ni * 16 + lr) * 32 + g * 8);
#pragma unroll
    for (int mi = 0; mi < 4; ++mi)
#pragma unroll
      for (int ni = 0; ni < 4; ++ni)
        acc[mi][ni] = __builtin_amdgcn_mfma_f32_16x16x32_bf16(af[mi], bv[ni], acc[mi][ni], 0, 0, 0);
  }
}

// GEMM1: qkv = x @ Wqkv ; Q PRE-SCALED by log2(e)/sqrt(64); V stored ROW-MAJOR
// [bh][s][d] (coalesced like K) — transpose_v produces the attn layout.
__global__ __launch_bounds__(256) void gemm_qkv_k(const bf16_t* __restrict__ xb,
                                                  const bf16_t* __restrict__ wt,
                                                  bf16_t* __restrict__ Qo,
                                                  bf16_t* __restrict__ Ko,
                                                  bf16_t* __restrict__ Vrow) {
  __shared__ bf16_t lA[128 * 32], lB[128 * 32];
  const int bm = blockIdx.x, bn = blockIdx.y;
  f32x4 acc[4][4] = {};
  gemm128_compute<1024>(xb, wt, lA, lB, acc, bm, bn);
  const float cs = 0.18033688011112042f;
  const int t = threadIdx.x, lr = t & 15, g = (t >> 4) & 3, w = t >> 6, wr = w >> 1, wc = w & 1;
  const int row0 = bm * 128 + wr * 64, col0 = bn * 128 + wc * 64;
#pragma unroll
  for (int mi = 0; mi < 4; ++mi) {
    const int row = row0 + mi * 16 + g * 4;
    const int b = row >> 11, s = row & 2047;
#pragma unroll
    for (int ni = 0; ni < 4; ++ni) {
      const int col = col0 + ni * 16 + lr;
      const int t3 = col >> 10, rem = col & 1023, h = rem >> 6, d = rem & 63;
      const int bh = b * 16 + h;
#pragma unroll
      for (int r = 0; r < 4; ++r) {
        const float av = acc[mi][ni][r];
        if (t3 == 0)      Qo[((size_t)bh * 2048 + s + r) * 64 + d] = (bf16_t)(av * cs);
        else if (t3 == 1) Ko[((size_t)bh * 2048 + s + r) * 64 + d] = (bf16_t)av;
        else              Vrow[((size_t)bh * 2048 + s + r) * 64 + d] = (bf16_t)av;
      }
    }
  }
}

__global__ __launch_bounds__(256) void gemm_o_k(const bf16_t* __restrict__ attn,
                                                const bf16_t* __restrict__ wot,
                                                float* __restrict__ out) {
  __shared__ bf16_t lA[128 * 32], lB[128 * 32];
  const int bm = blockIdx.x, bn = blockIdx.y;
  f32x4 acc[4][4] = {};
  gemm128_compute<1024>(attn, wot, lA, lB, acc, bm, bn);
  const int t = threadIdx.x, lr = t & 15, g = (t >> 4) & 3, w = t >> 6, wr = w >> 1, wc = w & 1;
  const int row0 = bm * 128 + wr * 64, col0 = bn * 128 + wc * 64;
#pragma unroll
  for (int mi = 0; mi < 4; ++mi) {
    const int row = row0 + mi * 16 + g * 4;
#pragma unroll
    for (int ni = 0; ni < 4; ++ni) {
      const int col = col0 + ni * 16 + lr;
#pragma unroll
      for (int r = 0; r < 4; ++r)
        out[(size_t)(row + r) * 1024 + col] = acc[mi][ni][r];
    }
  }
}

// ---------------- flash attention: counted-vmcnt pipeline (T4) + setprio ------
// grid (16,32) XCD-swizzled. Q(pre-scaled),K: [bh][2048][64]; Vperm: [bh][64][2048']
// (kv quad-swapped); Ao: [b][s][h*64+d].  (unchanged from r11)
__global__ __launch_bounds__(256, 2) void attn_k(const bf16_t* __restrict__ Q,
                                                 const bf16_t* __restrict__ K,
                                                 const bf16_t* __restrict__ Vt,
                                                 bf16_t* __restrict__ Ao) {
  __shared__ __align__(16) char smem[32768];  // kb0,kb1,vb0,vb1 (8KB each)
  const int t = threadIdx.x, w = t >> 6, l = t & 63;
  const int ql = l & 31, hi = l >> 5;
  const int orig = blockIdx.y * 16 + blockIdx.x;
  const int swz = (orig & 7) * 64 + (orig >> 3);
  const int qblk = swz & 15, bh = swz >> 4;
  const int b = bh >> 4, h = bh & 15;
  const bf16_t* Qb = Q  + (size_t)bh * 2048 * 64;
  const bf16_t* Kb = K  + (size_t)bh * 2048 * 64;
  const bf16_t* Vb = Vt + (size_t)bh * 64 * 2048;
  const int q0 = qblk * 128 + w * 32;

  const bf16_t* ksrc = Kb + (size_t)l * 64 + w * 8;
  const bf16_t* vsrc = Vb + (size_t)l * 2048 + w * 8;

  char* const kb0 = smem;
  char* const kb1 = smem + 8192;
  char* const vb0 = smem + 16384;
  char* const vb1 = smem + 24576;

  const bf16_t* qp = Qb + (size_t)(q0 + ql) * 64 + hi * 8;
  const bf16x8 qf0 = *(const bf16x8*)(qp);
  const bf16x8 qf1 = *(const bf16x8*)(qp + 16);
  const bf16x8 qf2 = *(const bf16x8*)(qp + 32);
  const bf16x8 qf3 = *(const bf16x8*)(qp + 48);

  bf16x8 ones;
#pragma unroll
  for (int i = 0; i < 8; ++i) ones[i] = (bf16_t)1.0f;

  f32x16 ot0 = {}, ot1 = {}, otls = {};

  auto stageK = [&](int tile, char* dst) {
    const bf16_t* ks = ksrc + (size_t)tile * 4096;
    gld_lds16(ks,      dst + w * 1024);
    gld_lds16(ks + 32, dst + (4 + w) * 1024);
  };
  auto stageV = [&](int tile, char* dst) {
    const bf16_t* vs = vsrc + (size_t)tile * 64;
    gld_lds16(vs,      dst + w * 1024);
    gld_lds16(vs + 32, dst + (4 + w) * 1024);
  };
  auto qk = [&](const char* kbuf, f32x16& sa, f32x16& sb) {
    const bf16x8 ka0 = *(const bf16x8*)(kbuf + (0 + hi) * 1024 + ql * 16);
    const bf16x8 ka1 = *(const bf16x8*)(kbuf + (2 + hi) * 1024 + ql * 16);
    const bf16x8 ka2 = *(const bf16x8*)(kbuf + (4 + hi) * 1024 + ql * 16);
    const bf16x8 ka3 = *(const bf16x8*)(kbuf + (6 + hi) * 1024 + ql * 16);
    sa = __builtin_amdgcn_mfma_f32_32x32x16_bf16(ka0, qf0, sa, 0, 0, 0);
    sa = __builtin_amdgcn_mfma_f32_32x32x16_bf16(ka1, qf1, sa, 0, 0, 0);
    sa = __builtin_amdgcn_mfma_f32_32x32x16_bf16(ka2, qf2, sa, 0, 0, 0);
    sa = __builtin_amdgcn_mfma_f32_32x32x16_bf16(ka3, qf3, sa, 0, 0, 0);
    const bf16x8 kb0f = *(const bf16x8*)(kbuf + (0 + hi) * 1024 + 512 + ql * 16);
    const bf16x8 kb1f = *(const bf16x8*)(kbuf + (2 + hi) * 1024 + 512 + ql * 16);
    const bf16x8 kb2f = *(const bf16x8*)(kbuf + (4 + hi) * 1024 + 512 + ql * 16);
    const bf16x8 kb3f = *(const bf16x8*)(kbuf + (6 + hi) * 1024 + 512 + ql * 16);
    sb = __builtin_amdgcn_mfma_f32_32x32x16_bf16(kb0f, qf0, sb, 0, 0, 0);
    sb = __builtin_amdgcn_mfma_f32_32x32x16_bf16(kb1f, qf1, sb, 0, 0, 0);
    sb = __builtin_amdgcn_mfma_f32_32x32x16_bf16(kb2f, qf2, sb, 0, 0, 0);
    sb = __builtin_amdgcn_mfma_f32_32x32x16_bf16(kb3f, qf3, sb, 0, 0, 0);
  };
  auto sm_pv = [&](const f32x16& sa, const f32x16& sb, const char* vread) {
    uint4v u0 = {pk2t(exp2f(sa[0]),  exp2f(sa[1])),  pk2t(exp2f(sa[2]),  exp2f(sa[3])),
                 pk2t(exp2f(sa[4]),  exp2f(sa[5])),  pk2t(exp2f(sa[6]),  exp2f(sa[7]))};
    uint4v u1 = {pk2t(exp2f(sa[8]),  exp2f(sa[9])),  pk2t(exp2f(sa[10]), exp2f(sa[11])),
                 pk2t(exp2f(sa[12]), exp2f(sa[13])), pk2t(exp2f(sa[14]), exp2f(sa[15]))};
    uint4v u2 = {pk2t(exp2f(sb[0]),  exp2f(sb[1])),  pk2t(exp2f(sb[2]),  exp2f(sb[3])),
                 pk2t(exp2f(sb[4]),  exp2f(sb[5])),  pk2t(exp2f(sb[6]),  exp2f(sb[7]))};
    uint4v u3 = {pk2t(exp2f(sb[8]),  exp2f(sb[9])),  pk2t(exp2f(sb[10]), exp2f(sb[11])),
                 pk2t(exp2f(sb[12]), exp2f(sb[13])), pk2t(exp2f(sb[14]), exp2f(sb[15]))};
    const bf16x8 pf0 = __builtin_bit_cast(bf16x8, u0);
    const bf16x8 pf1 = __builtin_bit_cast(bf16x8, u1);
    const bf16x8 pf2 = __builtin_bit_cast(bf16x8, u2);
    const bf16x8 pf3 = __builtin_bit_cast(bf16x8, u3);
    const bf16x8 v00 = *(const bf16x8*)(vread + (0 + hi) * 1024 + ql * 16);
    const bf16x8 v01 = *(const bf16x8*)(vread + (2 + hi) * 1024 + ql * 16);
    const bf16x8 v02 = *(const bf16x8*)(vread + (4 + hi) * 1024 + ql * 16);
    const bf16x8 v03 = *(const bf16x8*)(vread + (6 + hi) * 1024 + ql * 16);
    const bf16x8 v10 = *(const bf16x8*)(vread + (0 + hi) * 1024 + 512 + ql * 16);
    const bf16x8 v11 = *(const bf16x8*)(vread + (2 + hi) * 1024 + 512 + ql * 16);
    const bf16x8 v12 = *(const bf16x8*)(vread + (4 + hi) * 1024 + 512 + ql * 16);
    const bf16x8 v13 = *(const bf16x8*)(vread + (6 + hi) * 1024 + 512 + ql * 16);
    ot0  = __builtin_amdgcn_mfma_f32_32x32x16_bf16(v00,  pf0, ot0, 0, 0, 0);
    ot1  = __builtin_amdgcn_mfma_f32_32x32x16_bf16(v10,  pf0, ot1, 0, 0, 0);
    otls = __builtin_amdgcn_mfma_f32_32x32x16_bf16(ones, pf0, otls, 0, 0, 0);
    ot0  = __builtin_amdgcn_mfma_f32_32x32x16_bf16(v01,  pf1, ot0, 0, 0, 0);
    ot1  = __builtin_amdgcn_mfma_f32_32x32x16_bf16(v11,  pf1, ot1, 0, 0, 0);
    otls = __builtin_amdgcn_mfma_f32_32x32x16_bf16(ones, pf1, otls, 0, 0, 0);
    ot0  = __builtin_amdgcn_mfma_f32_32x32x16_bf16(v02,  pf2, ot0, 0, 0, 0);
    ot1  = __builtin_amdgcn_mfma_f32_32x32x16_bf16(v12,  pf2, ot1, 0, 0, 0);
    otls = __builtin_amdgcn_mfma_f32_32x32x16_bf16(ones, pf2, otls, 0, 0, 0);
    ot0  = __builtin_amdgcn_mfma_f32_32x32x16_bf16(v03,  pf3, ot0, 0, 0, 0);
    ot1  = __builtin_amdgcn_mfma_f32_32x32x16_bf16(v13,  pf3, ot1, 0, 0, 0);
    otls = __builtin_amdgcn_mfma_f32_32x32x16_bf16(ones, pf3, otls, 0, 0, 0);
  };

  // prologue: issue K(0),V(0),K(1); wait K0+V0 (vmcnt(4) leaves K1 in flight)
  stageK(0, kb0);
  stageV(0, vb0);
  stageK(1, kb1);
  asm volatile("s_waitcnt vmcnt(4)" ::: "memory");
  __builtin_amdgcn_sched_barrier(0);
  __builtin_amdgcn_s_barrier();
  f32x16 sca = {}, scb = {};
  qk(kb0, sca, scb);
  __builtin_amdgcn_s_barrier();

  auto body = [&](int j, char* kstage, const char* kread, const char* vread, char* vstage) {
    if (j < 31) stageV(j + 1, vstage);   // queue order: V first, then K
    if (j < 30) stageK(j + 2, kstage);
    if (j < 30)      asm volatile("s_waitcnt vmcnt(4)" ::: "memory");
    else if (j == 30) asm volatile("s_waitcnt vmcnt(2)" ::: "memory");
    else             asm volatile("s_waitcnt vmcnt(0)" ::: "memory");
    __builtin_amdgcn_sched_barrier(0);
    __builtin_amdgcn_s_barrier();        // K(j+1), V(j) resident for all waves
    f32x16 sna = {}, snb = {};
    __builtin_amdgcn_s_setprio(1);
    if (j < 31) qk(kread, sna, snb);     // QK(j+1) on MFMA pipe
    sm_pv(sca, scb, vread);              // exp/pack in QK's shadow, then PV(j)
    __builtin_amdgcn_s_setprio(0);
    __builtin_amdgcn_sched_barrier(0);
    __builtin_amdgcn_s_barrier();        // reads consumed before next restage
    sca = sna; scb = snb;
  };

#pragma unroll 2
  for (int j = 0; j < 32; ++j) {
    if ((j & 1) == 0) body(j, kb0, kb1, vb0, vb1);
    else              body(j, kb1, kb0, vb1, vb0);
  }

  // epilogue: normalize, transpose via XOR-swizzled LDS (reuse smem), store
  const float inv = 1.0f / otls[0];
  bf16_t* ob = (bf16_t*)(smem + w * 4096);
#pragma unroll
  for (int rg = 0; rg < 4; ++rg) {
    const int d0 = rg * 8 + hi * 4;
    bf16x4 v0, v1;
#pragma unroll
    for (int j = 0; j < 4; ++j) {
      v0[j] = (bf16_t)(ot0[4 * rg + j] * inv);
      v1[j] = (bf16_t)(ot1[4 * rg + j] * inv);
    }
    *(bf16x4*)((char*)ob + ql * 128 + (((d0)      * 2) ^ ((ql & 7) << 4))) = v0;
    *(bf16x4*)((char*)ob + ql * 128 + (((d0 + 32) * 2) ^ ((ql & 7) << 4))) = v1;
  }
  __syncthreads();
#pragma unroll
  for (int i = 0; i < 4; ++i) {
    const int c = i * 64 + l;
    const int qq = c >> 3, ch = c & 7;
    bf16x8 vv = *(const bf16x8*)((char*)ob + qq * 128 + ((ch * 16) ^ ((qq & 7) << 4)));
    *(bf16x8*)(Ao + (size_t)(b * 2048 + q0 + qq) * 1024 + h * 64 + ch * 8) = vv;
  }
}

// ---------------- launcher ----------------

extern "C" void kernel_launch(void* const* d_in, const int* in_sizes, int n_in,
                              void* d_out, int out_size, void* d_ws, size_t ws_size,
                              hipStream_t stream) {
  const float* x    = (const float*)d_in[0];  // [2,2048,1024]
  const float* wqkv = (const float*)d_in[1];  // [1024,3072]
  const float* wo   = (const float*)d_in[2];  // [1024,1024]
  float* out = (float*)d_out;

  char* ws = (char*)d_ws;
  bf16_t* xb    = (bf16_t*)(ws);                        // 8 MB  [4096][1024]
  bf16_t* wqkvT = (bf16_t*)(ws + (size_t)(8u  << 20));  // 6 MB  [3072][1024]
  bf16_t* woT   = (bf16_t*)(ws + (size_t)(14u << 20));  // 2 MB  [1024][1024]
  bf16_t* Qb    = (bf16_t*)(ws + (size_t)(16u << 20));  // 8 MB  [32][2048][64]
  bf16_t* Kb    = (bf16_t*)(ws + (size_t)(24u << 20));  // 8 MB
  bf16_t* Vtb   = (bf16_t*)(ws + (size_t)(32u << 20));  // 8 MB  [32][64][2048] (kv-permuted)
  bf16_t* attn  = (bf16_t*)(ws + (size_t)(40u << 20));  // 8 MB  [4096][1024]
  bf16_t* Vrow  = (bf16_t*)(ws + (size_t)(48u << 20));  // 8 MB  [32][2048][64]

  convert_f32_bf16<<<4096, 256, 0, stream>>>(x, xb, 4096 * 1024 / 4);
  transpose_w<<<dim3(96, 32), 256, 0, stream>>>(wqkv, wqkvT, 1024, 3072);
  transpose_w<<<dim3(32, 32), 256, 0, stream>>>(wo, woT, 1024, 1024);
  gemm_qkv_k<<<dim3(32, 24), 256, 0, stream>>>(xb, wqkvT, Qb, Kb, Vrow);
  transpose_v<<<dim3(2, 64, 32), 256, 0, stream>>>(Vrow, Vtb);
  attn_k<<<dim3(16, 32), 256, 0, stream>>>(Qb, Kb, Vtb, attn);
  gemm_o_k<<<dim3(32, 8), 256, 0, stream>>>(attn, woT, out);
}

// Round 13
// 120.670 us; speedup vs baseline: 1.0978x; 1.0978x over previous
//
#include <hip/hip_runtime.h>
#include <hip/hip_bf16.h>
#include <cstdint>

typedef __bf16 bf16_t;
typedef __bf16 bf16x8 __attribute__((ext_vector_type(8)));
typedef __bf16 bf16x4 __attribute__((ext_vector_type(4)));
typedef __bf16 bf16x2 __attribute__((ext_vector_type(2)));
typedef float  f32x4  __attribute__((ext_vector_type(4)));
typedef float  f32x16 __attribute__((ext_vector_type(16)));
typedef unsigned uint4v __attribute__((ext_vector_type(4)));

#define AS1 __attribute__((address_space(1)))
#define AS3 __attribute__((address_space(3)))

static __device__ __forceinline__ void gld_lds16(const void* g, void* l) {
  __builtin_amdgcn_global_load_lds((AS1 void*)g, (AS3 void*)l, 16, 0, 0);
}

// truncation-pack two f32 -> bf16x2 word via one v_perm_b32 (lo=a, hi=b).
// Bias cancels in O = sum(pV)/sum(p) since ls uses the same truncated P.
static __device__ __forceinline__ unsigned pk2t(float a, float b) {
  return __builtin_amdgcn_perm(__builtin_bit_cast(unsigned, a),
                               __builtin_bit_cast(unsigned, b), 0x03020706u);
}

// ---------------- fused prep: convert x + transpose both weights -------------
// blocks [0,4096): convert x f32->bf16 (float4/lane)
// blocks [4096,7168): transpose wqkv [1024][3072] -> [3072][1024] bf16
// blocks [7168,8192): transpose wo   [1024][1024] -> [1024][1024] bf16
__global__ __launch_bounds__(256) void prep_k(const float* __restrict__ x,
                                              bf16_t* __restrict__ xb,
                                              const float* __restrict__ wqkv,
                                              bf16_t* __restrict__ wqkvT,
                                              const float* __restrict__ wo,
                                              bf16_t* __restrict__ woT) {
  int bid = blockIdx.x;
  if (bid < 4096) {
    const int i = bid * 256 + threadIdx.x;
    float4 v = ((const float4*)x)[i];
    bf16x4 o;
    o[0] = (bf16_t)v.x; o[1] = (bf16_t)v.y; o[2] = (bf16_t)v.z; o[3] = (bf16_t)v.w;
    *(bf16x4*)(xb + (size_t)i * 4) = o;
    return;
  }
  __shared__ float tile[32][33];
  const float* in; bf16_t* out; int N, bx, by;
  if (bid < 7168) { bid -= 4096; in = wqkv; out = wqkvT; N = 3072; bx = bid % 96; by = bid / 96; }
  else            { bid -= 7168; in = wo;   out = woT;   N = 1024; bx = bid & 31; by = bid >> 5; }
  const int t = threadIdx.x, c = t & 31, r0 = t >> 5;
#pragma unroll
  for (int i = 0; i < 4; ++i) {
    int r = r0 + i * 8;
    tile[r][c] = in[(size_t)(by * 32 + r) * N + bx * 32 + c];
  }
  __syncthreads();
#pragma unroll
  for (int i = 0; i < 4; ++i) {
    int r = r0 + i * 8;
    out[(size_t)(bx * 32 + r) * 1024 + by * 32 + c] = (bf16_t)tile[c][r];
  }
}

// ---------------- 128x128 bf16 GEMM core: counted-vmcnt dbuf pipeline ---------
// BK=32, LDS 32KB (A/B x 2 buffers). Per iter: stage(j+1) -> buf^1 (4 gld_lds),
// vmcnt(4) (waits only tile j's loads; j+1's stay in flight across the barrier),
// s_barrier, ds_read frags, 16 MFMA (setprio), s_barrier. r11-attn-proven.
template <int KDIM>
static __device__ __forceinline__ void gemm128_pipe(const bf16_t* __restrict__ A,
                                                    const bf16_t* __restrict__ Bt,
                                                    char* lds, f32x4 acc[4][4],
                                                    int bm, int bn) {
  constexpr int NK = KDIM / 32;
  const int t = threadIdx.x;
  const int lr = t & 15, g = (t >> 4) & 3;
  const int w = t >> 6, wr = w >> 1, wc = w & 1;
  char* const la0 = lds;
  char* const la1 = lds + 8192;
  char* const lb0 = lds + 16384;
  char* const lb1 = lds + 24576;

  auto stage = [&](int i, char* la, char* lb) {
    const int kt = i * 32;
#pragma unroll
    for (int c = 0; c < 2; ++c) {
      const int idx = c * 256 + t;
      const int row = idx >> 2, cb = idx & 3;
      const int off = ((t & 192) + c * 256) * 16;
      gld_lds16(A  + (size_t)(bm * 128 + row) * KDIM + kt + cb * 8, la + off);
      gld_lds16(Bt + (size_t)(bn * 128 + row) * KDIM + kt + cb * 8, lb + off);
    }
  };

  stage(0, la0, lb0);
  asm volatile("s_waitcnt vmcnt(0)" ::: "memory");
  __builtin_amdgcn_sched_barrier(0);
  __builtin_amdgcn_s_barrier();

  auto body = [&](int j, char* laR, char* lbR, char* laS, char* lbS) {
    if (j + 1 < NK) {
      stage(j + 1, laS, lbS);
      asm volatile("s_waitcnt vmcnt(4)" ::: "memory");
    } else {
      asm volatile("s_waitcnt vmcnt(0)" ::: "memory");
    }
    __builtin_amdgcn_sched_barrier(0);
    __builtin_amdgcn_s_barrier();
    bf16x8 af[4], bv[4];
#pragma unroll
    for (int mi = 0; mi < 4; ++mi)
      af[mi] = *(const bf16x8*)(laR + (wr * 64 + mi * 16 + lr) * 64 + g * 16);
#pragma unroll
    for (int ni = 0; ni < 4; ++ni)
      bv[ni] = *(const bf16x8*)(lbR + (wc * 64 + ni * 16 + lr) * 64 + g * 16);
    __builtin_amdgcn_s_setprio(1);
#pragma unroll
    for (int mi = 0; mi < 4; ++mi)
#pragma unroll
      for (int ni = 0; ni < 4; ++ni)
        acc[mi][ni] = __builtin_amdgcn_mfma_f32_16x16x32_bf16(af[mi], bv[ni], acc[mi][ni], 0, 0, 0);
    __builtin_amdgcn_s_setprio(0);
    __builtin_amdgcn_sched_barrier(0);
    __builtin_amdgcn_s_barrier();
  };

#pragma unroll 2
  for (int j = 0; j < NK; ++j) {
    if ((j & 1) == 0) body(j, la0, lb0, la1, lb1);
    else              body(j, la1, lb1, la0, lb0);
  }
}

// GEMM1: qkv = x @ Wqkv ; Q PRE-SCALED by log2(e)/sqrt(64); V stored with
// quad-swapped kv order so attn PV A-fragments are contiguous 16B in LDS.
__global__ __launch_bounds__(256) void gemm_qkv_k(const bf16_t* __restrict__ xb,
                                                  const bf16_t* __restrict__ wt,
                                                  bf16_t* __restrict__ Qo,
                                                  bf16_t* __restrict__ Ko,
                                                  bf16_t* __restrict__ Vto) {
  __shared__ __align__(16) char lds[32768];
  const int bm = blockIdx.x, bn = blockIdx.y;
  f32x4 acc[4][4] = {};
  gemm128_pipe<1024>(xb, wt, lds, acc, bm, bn);
  const float cs = 0.18033688011112042f;
  const int t = threadIdx.x, lr = t & 15, g = (t >> 4) & 3, w = t >> 6, wr = w >> 1, wc = w & 1;
  const int row0 = bm * 128 + wr * 64, col0 = bn * 128 + wc * 64;
#pragma unroll
  for (int mi = 0; mi < 4; ++mi) {
    const int row = row0 + mi * 16 + g * 4;
    const int b = row >> 11, s = row & 2047;
#pragma unroll
    for (int ni = 0; ni < 4; ++ni) {
      const int col = col0 + ni * 16 + lr;
      const int t3 = col >> 10, rem = col & 1023, h = rem >> 6, d = rem & 63;
      const int bh = b * 16 + h;
#pragma unroll
      for (int r = 0; r < 4; ++r) {
        const float av = acc[mi][ni][r];
        if (t3 == 0)      Qo[((size_t)bh * 2048 + s + r) * 64 + d] = (bf16_t)(av * cs);
        else if (t3 == 1) Ko[((size_t)bh * 2048 + s + r) * 64 + d] = (bf16_t)av;
        else {
          const int kv = s + r;
          const int q3 = (kv >> 2) & 7;
          const int dq = (q3 & 4) | ((q3 & 1) << 1) | ((q3 >> 1) & 1);
          const int kvp = (kv & ~31) | (dq << 2) | (kv & 3);
          Vto[((size_t)bh * 64 + d) * 2048 + kvp] = (bf16_t)av;
        }
      }
    }
  }
}

__global__ __launch_bounds__(256) void gemm_o_k(const bf16_t* __restrict__ attn,
                                                const bf16_t* __restrict__ wot,
                                                float* __restrict__ out) {
  __shared__ __align__(16) char lds[32768];
  const int bm = blockIdx.x, bn = blockIdx.y;
  f32x4 acc[4][4] = {};
  gemm128_pipe<1024>(attn, wot, lds, acc, bm, bn);
  const int t = threadIdx.x, lr = t & 15, g = (t >> 4) & 3, w = t >> 6, wr = w >> 1, wc = w & 1;
  const int row0 = bm * 128 + wr * 64, col0 = bn * 128 + wc * 64;
#pragma unroll
  for (int mi = 0; mi < 4; ++mi) {
    const int row = row0 + mi * 16 + g * 4;
#pragma unroll
    for (int ni = 0; ni < 4; ++ni) {
      const int col = col0 + ni * 16 + lr;
#pragma unroll
      for (int r = 0; r < 4; ++r)
        out[(size_t)(row + r) * 1024 + col] = acc[mi][ni][r];
    }
  }
}

// ---------------- flash attention: counted-vmcnt pipeline (T4) + setprio ------
// grid (16,32) XCD-swizzled. Q(pre-scaled),K: [bh][2048][64]; Vperm: [bh][64][2048']
// (kv quad-swapped); Ao: [b][s][h*64+d].  (unchanged from r11)
__global__ __launch_bounds__(256, 2) void attn_k(const bf16_t* __restrict__ Q,
                                                 const bf16_t* __restrict__ K,
                                                 const bf16_t* __restrict__ Vt,
                                                 bf16_t* __restrict__ Ao) {
  __shared__ __align__(16) char smem[32768];  // kb0,kb1,vb0,vb1 (8KB each)
  const int t = threadIdx.x, w = t >> 6, l = t & 63;
  const int ql = l & 31, hi = l >> 5;
  const int orig = blockIdx.y * 16 + blockIdx.x;
  const int swz = (orig & 7) * 64 + (orig >> 3);
  const int qblk = swz & 15, bh = swz >> 4;
  const int b = bh >> 4, h = bh & 15;
  const bf16_t* Qb = Q  + (size_t)bh * 2048 * 64;
  const bf16_t* Kb = K  + (size_t)bh * 2048 * 64;
  const bf16_t* Vb = Vt + (size_t)bh * 64 * 2048;
  const int q0 = qblk * 128 + w * 32;

  const bf16_t* ksrc = Kb + (size_t)l * 64 + w * 8;
  const bf16_t* vsrc = Vb + (size_t)l * 2048 + w * 8;

  char* const kb0 = smem;
  char* const kb1 = smem + 8192;
  char* const vb0 = smem + 16384;
  char* const vb1 = smem + 24576;

  const bf16_t* qp = Qb + (size_t)(q0 + ql) * 64 + hi * 8;
  const bf16x8 qf0 = *(const bf16x8*)(qp);
  const bf16x8 qf1 = *(const bf16x8*)(qp + 16);
  const bf16x8 qf2 = *(const bf16x8*)(qp + 32);
  const bf16x8 qf3 = *(const bf16x8*)(qp + 48);

  bf16x8 ones;
#pragma unroll
  for (int i = 0; i < 8; ++i) ones[i] = (bf16_t)1.0f;

  f32x16 ot0 = {}, ot1 = {}, otls = {};

  auto stageK = [&](int tile, char* dst) {
    const bf16_t* ks = ksrc + (size_t)tile * 4096;
    gld_lds16(ks,      dst + w * 1024);
    gld_lds16(ks + 32, dst + (4 + w) * 1024);
  };
  auto stageV = [&](int tile, char* dst) {
    const bf16_t* vs = vsrc + (size_t)tile * 64;
    gld_lds16(vs,      dst + w * 1024);
    gld_lds16(vs + 32, dst + (4 + w) * 1024);
  };
  auto qk = [&](const char* kbuf, f32x16& sa, f32x16& sb) {
    const bf16x8 ka0 = *(const bf16x8*)(kbuf + (0 + hi) * 1024 + ql * 16);
    const bf16x8 ka1 = *(const bf16x8*)(kbuf + (2 + hi) * 1024 + ql * 16);
    const bf16x8 ka2 = *(const bf16x8*)(kbuf + (4 + hi) * 1024 + ql * 16);
    const bf16x8 ka3 = *(const bf16x8*)(kbuf + (6 + hi) * 1024 + ql * 16);
    sa = __builtin_amdgcn_mfma_f32_32x32x16_bf16(ka0, qf0, sa, 0, 0, 0);
    sa = __builtin_amdgcn_mfma_f32_32x32x16_bf16(ka1, qf1, sa, 0, 0, 0);
    sa = __builtin_amdgcn_mfma_f32_32x32x16_bf16(ka2, qf2, sa, 0, 0, 0);
    sa = __builtin_amdgcn_mfma_f32_32x32x16_bf16(ka3, qf3, sa, 0, 0, 0);
    const bf16x8 kb0f = *(const bf16x8*)(kbuf + (0 + hi) * 1024 + 512 + ql * 16);
    const bf16x8 kb1f = *(const bf16x8*)(kbuf + (2 + hi) * 1024 + 512 + ql * 16);
    const bf16x8 kb2f = *(const bf16x8*)(kbuf + (4 + hi) * 1024 + 512 + ql * 16);
    const bf16x8 kb3f = *(const bf16x8*)(kbuf + (6 + hi) * 1024 + 512 + ql * 16);
    sb = __builtin_amdgcn_mfma_f32_32x32x16_bf16(kb0f, qf0, sb, 0, 0, 0);
    sb = __builtin_amdgcn_mfma_f32_32x32x16_bf16(kb1f, qf1, sb, 0, 0, 0);
    sb = __builtin_amdgcn_mfma_f32_32x32x16_bf16(kb2f, qf2, sb, 0, 0, 0);
    sb = __builtin_amdgcn_mfma_f32_32x32x16_bf16(kb3f, qf3, sb, 0, 0, 0);
  };
  auto sm_pv = [&](const f32x16& sa, const f32x16& sb, const char* vread) {
    uint4v u0 = {pk2t(exp2f(sa[0]),  exp2f(sa[1])),  pk2t(exp2f(sa[2]),  exp2f(sa[3])),
                 pk2t(exp2f(sa[4]),  exp2f(sa[5])),  pk2t(exp2f(sa[6]),  exp2f(sa[7]))};
    uint4v u1 = {pk2t(exp2f(sa[8]),  exp2f(sa[9])),  pk2t(exp2f(sa[10]), exp2f(sa[11])),
                 pk2t(exp2f(sa[12]), exp2f(sa[13])), pk2t(exp2f(sa[14]), exp2f(sa[15]))};
    uint4v u2 = {pk2t(exp2f(sb[0]),  exp2f(sb[1])),  pk2t(exp2f(sb[2]),  exp2f(sb[3])),
                 pk2t(exp2f(sb[4]),  exp2f(sb[5])),  pk2t(exp2f(sb[6]),  exp2f(sb[7]))};
    uint4v u3 = {pk2t(exp2f(sb[8]),  exp2f(sb[9])),  pk2t(exp2f(sb[10]), exp2f(sb[11])),
                 pk2t(exp2f(sb[12]), exp2f(sb[13])), pk2t(exp2f(sb[14]), exp2f(sb[15]))};
    const bf16x8 pf0 = __builtin_bit_cast(bf16x8, u0);
    const bf16x8 pf1 = __builtin_bit_cast(bf16x8, u1);
    const bf16x8 pf2 = __builtin_bit_cast(bf16x8, u2);
    const bf16x8 pf3 = __builtin_bit_cast(bf16x8, u3);
    const bf16x8 v00 = *(const bf16x8*)(vread + (0 + hi) * 1024 + ql * 16);
    const bf16x8 v01 = *(const bf16x8*)(vread + (2 + hi) * 1024 + ql * 16);
    const bf16x8 v02 = *(const bf16x8*)(vread + (4 + hi) * 1024 + ql * 16);
    const bf16x8 v03 = *(const bf16x8*)(vread + (6 + hi) * 1024 + ql * 16);
    const bf16x8 v10 = *(const bf16x8*)(vread + (0 + hi) * 1024 + 512 + ql * 16);
    const bf16x8 v11 = *(const bf16x8*)(vread + (2 + hi) * 1024 + 512 + ql * 16);
    const bf16x8 v12 = *(const bf16x8*)(vread + (4 + hi) * 1024 + 512 + ql * 16);
    const bf16x8 v13 = *(const bf16x8*)(vread + (6 + hi) * 1024 + 512 + ql * 16);
    ot0  = __builtin_amdgcn_mfma_f32_32x32x16_bf16(v00,  pf0, ot0, 0, 0, 0);
    ot1  = __builtin_amdgcn_mfma_f32_32x32x16_bf16(v10,  pf0, ot1, 0, 0, 0);
    otls = __builtin_amdgcn_mfma_f32_32x32x16_bf16(ones, pf0, otls, 0, 0, 0);
    ot0  = __builtin_amdgcn_mfma_f32_32x32x16_bf16(v01,  pf1, ot0, 0, 0, 0);
    ot1  = __builtin_amdgcn_mfma_f32_32x32x16_bf16(v11,  pf1, ot1, 0, 0, 0);
    otls = __builtin_amdgcn_mfma_f32_32x32x16_bf16(ones, pf1, otls, 0, 0, 0);
    ot0  = __builtin_amdgcn_mfma_f32_32x32x16_bf16(v02,  pf2, ot0, 0, 0, 0);
    ot1  = __builtin_amdgcn_mfma_f32_32x32x16_bf16(v12,  pf2, ot1, 0, 0, 0);
    otls = __builtin_amdgcn_mfma_f32_32x32x16_bf16(ones, pf2, otls, 0, 0, 0);
    ot0  = __builtin_amdgcn_mfma_f32_32x32x16_bf16(v03,  pf3, ot0, 0, 0, 0);
    ot1  = __builtin_amdgcn_mfma_f32_32x32x16_bf16(v13,  pf3, ot1, 0, 0, 0);
    otls = __builtin_amdgcn_mfma_f32_32x32x16_bf16(ones, pf3, otls, 0, 0, 0);
  };

  // prologue: issue K(0),V(0),K(1); wait K0+V0 (vmcnt(4) leaves K1 in flight)
  stageK(0, kb0);
  stageV(0, vb0);
  stageK(1, kb1);
  asm volatile("s_waitcnt vmcnt(4)" ::: "memory");
  __builtin_amdgcn_sched_barrier(0);
  __builtin_amdgcn_s_barrier();
  f32x16 sca = {}, scb = {};
  qk(kb0, sca, scb);
  __builtin_amdgcn_s_barrier();

  auto body = [&](int j, char* kstage, const char* kread, const char* vread, char* vstage) {
    if (j < 31) stageV(j + 1, vstage);   // queue order: V first, then K
    if (j < 30) stageK(j + 2, kstage);
    if (j < 30)      asm volatile("s_waitcnt vmcnt(4)" ::: "memory");
    else if (j == 30) asm volatile("s_waitcnt vmcnt(2)" ::: "memory");
    else             asm volatile("s_waitcnt vmcnt(0)" ::: "memory");
    __builtin_amdgcn_sched_barrier(0);
    __builtin_amdgcn_s_barrier();        // K(j+1), V(j) resident for all waves
    f32x16 sna = {}, snb = {};
    __builtin_amdgcn_s_setprio(1);
    if (j < 31) qk(kread, sna, snb);     // QK(j+1) on MFMA pipe
    sm_pv(sca, scb, vread);              // exp/pack in QK's shadow, then PV(j)
    __builtin_amdgcn_s_setprio(0);
    __builtin_amdgcn_sched_barrier(0);
    __builtin_amdgcn_s_barrier();        // reads consumed before next restage
    sca = sna; scb = snb;
  };

#pragma unroll 2
  for (int j = 0; j < 32; ++j) {
    if ((j & 1) == 0) body(j, kb0, kb1, vb0, vb1);
    else              body(j, kb1, kb0, vb1, vb0);
  }

  // epilogue: normalize, transpose via XOR-swizzled LDS (reuse smem), store
  const float inv = 1.0f / otls[0];
  bf16_t* ob = (bf16_t*)(smem + w * 4096);
#pragma unroll
  for (int rg = 0; rg < 4; ++rg) {
    const int d0 = rg * 8 + hi * 4;
    bf16x4 v0, v1;
#pragma unroll
    for (int j = 0; j < 4; ++j) {
      v0[j] = (bf16_t)(ot0[4 * rg + j] * inv);
      v1[j] = (bf16_t)(ot1[4 * rg + j] * inv);
    }
    *(bf16x4*)((char*)ob + ql * 128 + (((d0)      * 2) ^ ((ql & 7) << 4))) = v0;
    *(bf16x4*)((char*)ob + ql * 128 + (((d0 + 32) * 2) ^ ((ql & 7) << 4))) = v1;
  }
  __syncthreads();
#pragma unroll
  for (int i = 0; i < 4; ++i) {
    const int c = i * 64 + l;
    const int qq = c >> 3, ch = c & 7;
    bf16x8 vv = *(const bf16x8*)((char*)ob + qq * 128 + ((ch * 16) ^ ((qq & 7) << 4)));
    *(bf16x8*)(Ao + (size_t)(b * 2048 + q0 + qq) * 1024 + h * 64 + ch * 8) = vv;
  }
}

// ---------------- launcher ----------------

extern "C" void kernel_launch(void* const* d_in, const int* in_sizes, int n_in,
                              void* d_out, int out_size, void* d_ws, size_t ws_size,
                              hipStream_t stream) {
  const float* x    = (const float*)d_in[0];  // [2,2048,1024]
  const float* wqkv = (const float*)d_in[1];  // [1024,3072]
  const float* wo   = (const float*)d_in[2];  // [1024,1024]
  float* out = (float*)d_out;

  char* ws = (char*)d_ws;
  bf16_t* xb    = (bf16_t*)(ws);                        // 8 MB  [4096][1024]
  bf16_t* wqkvT = (bf16_t*)(ws + (size_t)(8u  << 20));  // 6 MB  [3072][1024]
  bf16_t* woT   = (bf16_t*)(ws + (size_t)(14u << 20));  // 2 MB  [1024][1024]
  bf16_t* Qb    = (bf16_t*)(ws + (size_t)(16u << 20));  // 8 MB  [32][2048][64]
  bf16_t* Kb    = (bf16_t*)(ws + (size_t)(24u << 20));  // 8 MB
  bf16_t* Vtb   = (bf16_t*)(ws + (size_t)(32u << 20));  // 8 MB  [32][64][2048] (kv-permuted)
  bf16_t* attn  = (bf16_t*)(ws + (size_t)(40u << 20));  // 8 MB  [4096][1024]

  prep_k<<<8192, 256, 0, stream>>>(x, xb, wqkv, wqkvT, wo, woT);
  gemm_qkv_k<<<dim3(32, 24), 256, 0, stream>>>(xb, wqkvT, Qb, Kb, Vtb);
  attn_k<<<dim3(16, 32), 256, 0, stream>>>(Qb, Kb, Vtb, attn);
  gemm_o_k<<<dim3(32, 8), 256, 0, stream>>>(attn, woT, out);
}

// Round 14
// 119.011 us; speedup vs baseline: 1.1131x; 1.0139x over previous
//
#include <hip/hip_runtime.h>
#include <hip/hip_bf16.h>
#include <cstdint>

typedef __bf16 bf16_t;
typedef __bf16 bf16x8 __attribute__((ext_vector_type(8)));
typedef __bf16 bf16x4 __attribute__((ext_vector_type(4)));
typedef __bf16 bf16x2 __attribute__((ext_vector_type(2)));
typedef float  f32x4  __attribute__((ext_vector_type(4)));
typedef float  f32x16 __attribute__((ext_vector_type(16)));
typedef unsigned uint4v __attribute__((ext_vector_type(4)));

#define AS1 __attribute__((address_space(1)))
#define AS3 __attribute__((address_space(3)))

static __device__ __forceinline__ void gld_lds16(const void* g, void* l) {
  __builtin_amdgcn_global_load_lds((AS1 void*)g, (AS3 void*)l, 16, 0, 0);
}

// truncation-pack two f32 -> bf16x2 word via one v_perm_b32 (lo=a, hi=b).
// Bias cancels in O = sum(pV)/sum(p) since ls uses the same truncated P.
static __device__ __forceinline__ unsigned pk2t(float a, float b) {
  return __builtin_amdgcn_perm(__builtin_bit_cast(unsigned, a),
                               __builtin_bit_cast(unsigned, b), 0x03020706u);
}

// ---------------- fused prep: convert x + transpose both weights -------------
__global__ __launch_bounds__(256) void prep_k(const float* __restrict__ x,
                                              bf16_t* __restrict__ xb,
                                              const float* __restrict__ wqkv,
                                              bf16_t* __restrict__ wqkvT,
                                              const float* __restrict__ wo,
                                              bf16_t* __restrict__ woT) {
  int bid = blockIdx.x;
  if (bid < 4096) {
    const int i = bid * 256 + threadIdx.x;
    float4 v = ((const float4*)x)[i];
    bf16x4 o;
    o[0] = (bf16_t)v.x; o[1] = (bf16_t)v.y; o[2] = (bf16_t)v.z; o[3] = (bf16_t)v.w;
    *(bf16x4*)(xb + (size_t)i * 4) = o;
    return;
  }
  __shared__ float tile[32][33];
  const float* in; bf16_t* out; int N, bx, by;
  if (bid < 7168) { bid -= 4096; in = wqkv; out = wqkvT; N = 3072; bx = bid % 96; by = bid / 96; }
  else            { bid -= 7168; in = wo;   out = woT;   N = 1024; bx = bid & 31; by = bid >> 5; }
  const int t = threadIdx.x, c = t & 31, r0 = t >> 5;
#pragma unroll
  for (int i = 0; i < 4; ++i) {
    int r = r0 + i * 8;
    tile[r][c] = in[(size_t)(by * 32 + r) * N + bx * 32 + c];
  }
  __syncthreads();
#pragma unroll
  for (int i = 0; i < 4; ++i) {
    int r = r0 + i * 8;
    out[(size_t)(bx * 32 + r) * 1024 + by * 32 + c] = (bf16_t)tile[c][r];
  }
}

// ---------------- 128x128 bf16 GEMM core: depth-2 counted-vmcnt pipeline ------
// BK=32, LDS 48KB: A0..A2 (8KB each) at lds+0/8192/16384, B0..B2 at +24576/...
// Per iter j: stage(j+2) -> buf[(j+2)%3], vmcnt(8) (waits stage(j) done; j+1,
// j+2 stay in flight across 2 full iterations), s_barrier, ds_read frags,
// 16 MFMA (setprio), s_barrier. Tail: vmcnt(4) at NK-2, vmcnt(0) at NK-1.
// WAR: buf[(j+2)%3] was read at iter j-1, sealed by j-1's end barrier.
template <int KDIM>
static __device__ __forceinline__ void gemm128_pipe(const bf16_t* __restrict__ A,
                                                    const bf16_t* __restrict__ Bt,
                                                    char* lds, f32x4 acc[4][4],
                                                    int bm, int bn) {
  constexpr int NK = KDIM / 32;
  const int t = threadIdx.x;
  const int lr = t & 15, g = (t >> 4) & 3;
  const int w = t >> 6, wr = w >> 1, wc = w & 1;

  auto bufA = [&](int i) { return lds + (i % 3) * 8192; };
  auto bufB = [&](int i) { return lds + 24576 + (i % 3) * 8192; };

  auto stage = [&](int i) {
    const int kt = i * 32;
    char* la = bufA(i);
    char* lb = bufB(i);
#pragma unroll
    for (int c = 0; c < 2; ++c) {
      const int idx = c * 256 + t;
      const int row = idx >> 2, cb = idx & 3;
      const int off = ((t & 192) + c * 256) * 16;
      gld_lds16(A  + (size_t)(bm * 128 + row) * KDIM + kt + cb * 8, la + off);
      gld_lds16(Bt + (size_t)(bn * 128 + row) * KDIM + kt + cb * 8, lb + off);
    }
  };

  // prologue: tiles 0 and 1 issued; wait tile 0 (tile 1 stays in flight)
  stage(0);
  stage(1);
  asm volatile("s_waitcnt vmcnt(4)" ::: "memory");
  __builtin_amdgcn_sched_barrier(0);
  __builtin_amdgcn_s_barrier();

  for (int j = 0; j < NK; ++j) {
    if (j + 2 < NK) {
      stage(j + 2);
      asm volatile("s_waitcnt vmcnt(8)" ::: "memory");   // stage(j) done
    } else if (j + 1 < NK) {
      asm volatile("s_waitcnt vmcnt(4)" ::: "memory");   // j == NK-2
    } else {
      asm volatile("s_waitcnt vmcnt(0)" ::: "memory");   // j == NK-1
    }
    __builtin_amdgcn_sched_barrier(0);
    __builtin_amdgcn_s_barrier();        // tile j resident for all waves
    const char* laR = bufA(j);
    const char* lbR = bufB(j);
    bf16x8 af[4], bv[4];
#pragma unroll
    for (int mi = 0; mi < 4; ++mi)
      af[mi] = *(const bf16x8*)(laR + (wr * 64 + mi * 16 + lr) * 64 + g * 16);
#pragma unroll
    for (int ni = 0; ni < 4; ++ni)
      bv[ni] = *(const bf16x8*)(lbR + (wc * 64 + ni * 16 + lr) * 64 + g * 16);
    __builtin_amdgcn_s_setprio(1);
#pragma unroll
    for (int mi = 0; mi < 4; ++mi)
#pragma unroll
      for (int ni = 0; ni < 4; ++ni)
        acc[mi][ni] = __builtin_amdgcn_mfma_f32_16x16x32_bf16(af[mi], bv[ni], acc[mi][ni], 0, 0, 0);
    __builtin_amdgcn_s_setprio(0);
    __builtin_amdgcn_sched_barrier(0);
    __builtin_amdgcn_s_barrier();        // reads consumed before next restage
  }
}

// GEMM1: qkv = x @ Wqkv ; Q PRE-SCALED by log2(e)/sqrt(64); V stored with
// quad-swapped kv order so attn PV A-fragments are contiguous 16B in LDS.
__global__ __launch_bounds__(256) void gemm_qkv_k(const bf16_t* __restrict__ xb,
                                                  const bf16_t* __restrict__ wt,
                                                  bf16_t* __restrict__ Qo,
                                                  bf16_t* __restrict__ Ko,
                                                  bf16_t* __restrict__ Vto) {
  __shared__ __align__(16) char lds[49152];
  const int bm = blockIdx.x, bn = blockIdx.y;
  f32x4 acc[4][4] = {};
  gemm128_pipe<1024>(xb, wt, lds, acc, bm, bn);
  const float cs = 0.18033688011112042f;
  const int t = threadIdx.x, lr = t & 15, g = (t >> 4) & 3, w = t >> 6, wr = w >> 1, wc = w & 1;
  const int row0 = bm * 128 + wr * 64, col0 = bn * 128 + wc * 64;
#pragma unroll
  for (int mi = 0; mi < 4; ++mi) {
    const int row = row0 + mi * 16 + g * 4;
    const int b = row >> 11, s = row & 2047;
#pragma unroll
    for (int ni = 0; ni < 4; ++ni) {
      const int col = col0 + ni * 16 + lr;
      const int t3 = col >> 10, rem = col & 1023, h = rem >> 6, d = rem & 63;
      const int bh = b * 16 + h;
#pragma unroll
      for (int r = 0; r < 4; ++r) {
        const float av = acc[mi][ni][r];
        if (t3 == 0)      Qo[((size_t)bh * 2048 + s + r) * 64 + d] = (bf16_t)(av * cs);
        else if (t3 == 1) Ko[((size_t)bh * 2048 + s + r) * 64 + d] = (bf16_t)av;
        else {
          const int kv = s + r;
          const int q3 = (kv >> 2) & 7;
          const int dq = (q3 & 4) | ((q3 & 1) << 1) | ((q3 >> 1) & 1);
          const int kvp = (kv & ~31) | (dq << 2) | (kv & 3);
          Vto[((size_t)bh * 64 + d) * 2048 + kvp] = (bf16_t)av;
        }
      }
    }
  }
}

__global__ __launch_bounds__(256) void gemm_o_k(const bf16_t* __restrict__ attn,
                                                const bf16_t* __restrict__ wot,
                                                float* __restrict__ out) {
  __shared__ __align__(16) char lds[49152];
  const int bm = blockIdx.x, bn = blockIdx.y;
  f32x4 acc[4][4] = {};
  gemm128_pipe<1024>(attn, wot, lds, acc, bm, bn);
  const int t = threadIdx.x, lr = t & 15, g = (t >> 4) & 3, w = t >> 6, wr = w >> 1, wc = w & 1;
  const int row0 = bm * 128 + wr * 64, col0 = bn * 128 + wc * 64;
#pragma unroll
  for (int mi = 0; mi < 4; ++mi) {
    const int row = row0 + mi * 16 + g * 4;
#pragma unroll
    for (int ni = 0; ni < 4; ++ni) {
      const int col = col0 + ni * 16 + lr;
#pragma unroll
      for (int r = 0; r < 4; ++r)
        out[(size_t)(row + r) * 1024 + col] = acc[mi][ni][r];
    }
  }
}

// ---------------- flash attention: counted-vmcnt pipeline (T4) + setprio ------
// grid (16,32) XCD-swizzled. Q(pre-scaled),K: [bh][2048][64]; Vperm: [bh][64][2048']
// (kv quad-swapped); Ao: [b][s][h*64+d].  (unchanged from r11/r13)
__global__ __launch_bounds__(256, 2) void attn_k(const bf16_t* __restrict__ Q,
                                                 const bf16_t* __restrict__ K,
                                                 const bf16_t* __restrict__ Vt,
                                                 bf16_t* __restrict__ Ao) {
  __shared__ __align__(16) char smem[32768];  // kb0,kb1,vb0,vb1 (8KB each)
  const int t = threadIdx.x, w = t >> 6, l = t & 63;
  const int ql = l & 31, hi = l >> 5;
  const int orig = blockIdx.y * 16 + blockIdx.x;
  const int swz = (orig & 7) * 64 + (orig >> 3);
  const int qblk = swz & 15, bh = swz >> 4;
  const int b = bh >> 4, h = bh & 15;
  const bf16_t* Qb = Q  + (size_t)bh * 2048 * 64;
  const bf16_t* Kb = K  + (size_t)bh * 2048 * 64;
  const bf16_t* Vb = Vt + (size_t)bh * 64 * 2048;
  const int q0 = qblk * 128 + w * 32;

  const bf16_t* ksrc = Kb + (size_t)l * 64 + w * 8;
  const bf16_t* vsrc = Vb + (size_t)l * 2048 + w * 8;

  char* const kb0 = smem;
  char* const kb1 = smem + 8192;
  char* const vb0 = smem + 16384;
  char* const vb1 = smem + 24576;

  const bf16_t* qp = Qb + (size_t)(q0 + ql) * 64 + hi * 8;
  const bf16x8 qf0 = *(const bf16x8*)(qp);
  const bf16x8 qf1 = *(const bf16x8*)(qp + 16);
  const bf16x8 qf2 = *(const bf16x8*)(qp + 32);
  const bf16x8 qf3 = *(const bf16x8*)(qp + 48);

  bf16x8 ones;
#pragma unroll
  for (int i = 0; i < 8; ++i) ones[i] = (bf16_t)1.0f;

  f32x16 ot0 = {}, ot1 = {}, otls = {};

  auto stageK = [&](int tile, char* dst) {
    const bf16_t* ks = ksrc + (size_t)tile * 4096;
    gld_lds16(ks,      dst + w * 1024);
    gld_lds16(ks + 32, dst + (4 + w) * 1024);
  };
  auto stageV = [&](int tile, char* dst) {
    const bf16_t* vs = vsrc + (size_t)tile * 64;
    gld_lds16(vs,      dst + w * 1024);
    gld_lds16(vs + 32, dst + (4 + w) * 1024);
  };
  auto qk = [&](const char* kbuf, f32x16& sa, f32x16& sb) {
    const bf16x8 ka0 = *(const bf16x8*)(kbuf + (0 + hi) * 1024 + ql * 16);
    const bf16x8 ka1 = *(const bf16x8*)(kbuf + (2 + hi) * 1024 + ql * 16);
    const bf16x8 ka2 = *(const bf16x8*)(kbuf + (4 + hi) * 1024 + ql * 16);
    const bf16x8 ka3 = *(const bf16x8*)(kbuf + (6 + hi) * 1024 + ql * 16);
    sa = __builtin_amdgcn_mfma_f32_32x32x16_bf16(ka0, qf0, sa, 0, 0, 0);
    sa = __builtin_amdgcn_mfma_f32_32x32x16_bf16(ka1, qf1, sa, 0, 0, 0);
    sa = __builtin_amdgcn_mfma_f32_32x32x16_bf16(ka2, qf2, sa, 0, 0, 0);
    sa = __builtin_amdgcn_mfma_f32_32x32x16_bf16(ka3, qf3, sa, 0, 0, 0);
    const bf16x8 kb0f = *(const bf16x8*)(kbuf + (0 + hi) * 1024 + 512 + ql * 16);
    const bf16x8 kb1f = *(const bf16x8*)(kbuf + (2 + hi) * 1024 + 512 + ql * 16);
    const bf16x8 kb2f = *(const bf16x8*)(kbuf + (4 + hi) * 1024 + 512 + ql * 16);
    const bf16x8 kb3f = *(const bf16x8*)(kbuf + (6 + hi) * 1024 + 512 + ql * 16);
    sb = __builtin_amdgcn_mfma_f32_32x32x16_bf16(kb0f, qf0, sb, 0, 0, 0);
    sb = __builtin_amdgcn_mfma_f32_32x32x16_bf16(kb1f, qf1, sb, 0, 0, 0);
    sb = __builtin_amdgcn_mfma_f32_32x32x16_bf16(kb2f, qf2, sb, 0, 0, 0);
    sb = __builtin_amdgcn_mfma_f32_32x32x16_bf16(kb3f, qf3, sb, 0, 0, 0);
  };
  auto sm_pv = [&](const f32x16& sa, const f32x16& sb, const char* vread) {
    uint4v u0 = {pk2t(exp2f(sa[0]),  exp2f(sa[1])),  pk2t(exp2f(sa[2]),  exp2f(sa[3])),
                 pk2t(exp2f(sa[4]),  exp2f(sa[5])),  pk2t(exp2f(sa[6]),  exp2f(sa[7]))};
    uint4v u1 = {pk2t(exp2f(sa[8]),  exp2f(sa[9])),  pk2t(exp2f(sa[10]), exp2f(sa[11])),
                 pk2t(exp2f(sa[12]), exp2f(sa[13])), pk2t(exp2f(sa[14]), exp2f(sa[15]))};
    uint4v u2 = {pk2t(exp2f(sb[0]),  exp2f(sb[1])),  pk2t(exp2f(sb[2]),  exp2f(sb[3])),
                 pk2t(exp2f(sb[4]),  exp2f(sb[5])),  pk2t(exp2f(sb[6]),  exp2f(sb[7]))};
    uint4v u3 = {pk2t(exp2f(sb[8]),  exp2f(sb[9])),  pk2t(exp2f(sb[10]), exp2f(sb[11])),
                 pk2t(exp2f(sb[12]), exp2f(sb[13])), pk2t(exp2f(sb[14]), exp2f(sb[15]))};
    const bf16x8 pf0 = __builtin_bit_cast(bf16x8, u0);
    const bf16x8 pf1 = __builtin_bit_cast(bf16x8, u1);
    const bf16x8 pf2 = __builtin_bit_cast(bf16x8, u2);
    const bf16x8 pf3 = __builtin_bit_cast(bf16x8, u3);
    const bf16x8 v00 = *(const bf16x8*)(vread + (0 + hi) * 1024 + ql * 16);
    const bf16x8 v01 = *(const bf16x8*)(vread + (2 + hi) * 1024 + ql * 16);
    const bf16x8 v02 = *(const bf16x8*)(vread + (4 + hi) * 1024 + ql * 16);
    const bf16x8 v03 = *(const bf16x8*)(vread + (6 + hi) * 1024 + ql * 16);
    const bf16x8 v10 = *(const bf16x8*)(vread + (0 + hi) * 1024 + 512 + ql * 16);
    const bf16x8 v11 = *(const bf16x8*)(vread + (2 + hi) * 1024 + 512 + ql * 16);
    const bf16x8 v12 = *(const bf16x8*)(vread + (4 + hi) * 1024 + 512 + ql * 16);
    const bf16x8 v13 = *(const bf16x8*)(vread + (6 + hi) * 1024 + 512 + ql * 16);
    ot0  = __builtin_amdgcn_mfma_f32_32x32x16_bf16(v00,  pf0, ot0, 0, 0, 0);
    ot1  = __builtin_amdgcn_mfma_f32_32x32x16_bf16(v10,  pf0, ot1, 0, 0, 0);
    otls = __builtin_amdgcn_mfma_f32_32x32x16_bf16(ones, pf0, otls, 0, 0, 0);
    ot0  = __builtin_amdgcn_mfma_f32_32x32x16_bf16(v01,  pf1, ot0, 0, 0, 0);
    ot1  = __builtin_amdgcn_mfma_f32_32x32x16_bf16(v11,  pf1, ot1, 0, 0, 0);
    otls = __builtin_amdgcn_mfma_f32_32x32x16_bf16(ones, pf1, otls, 0, 0, 0);
    ot0  = __builtin_amdgcn_mfma_f32_32x32x16_bf16(v02,  pf2, ot0, 0, 0, 0);
    ot1  = __builtin_amdgcn_mfma_f32_32x32x16_bf16(v12,  pf2, ot1, 0, 0, 0);
    otls = __builtin_amdgcn_mfma_f32_32x32x16_bf16(ones, pf2, otls, 0, 0, 0);
    ot0  = __builtin_amdgcn_mfma_f32_32x32x16_bf16(v03,  pf3, ot0, 0, 0, 0);
    ot1  = __builtin_amdgcn_mfma_f32_32x32x16_bf16(v13,  pf3, ot1, 0, 0, 0);
    otls = __builtin_amdgcn_mfma_f32_32x32x16_bf16(ones, pf3, otls, 0, 0, 0);
  };

  // prologue: issue K(0),V(0),K(1); wait K0+V0 (vmcnt(4) leaves K1 in flight)
  stageK(0, kb0);
  stageV(0, vb0);
  stageK(1, kb1);
  asm volatile("s_waitcnt vmcnt(4)" ::: "memory");
  __builtin_amdgcn_sched_barrier(0);
  __builtin_amdgcn_s_barrier();
  f32x16 sca = {}, scb = {};
  qk(kb0, sca, scb);
  __builtin_amdgcn_s_barrier();

  auto body = [&](int j, char* kstage, const char* kread, const char* vread, char* vstage) {
    if (j < 31) stageV(j + 1, vstage);   // queue order: V first, then K
    if (j < 30) stageK(j + 2, kstage);
    if (j < 30)      asm volatile("s_waitcnt vmcnt(4)" ::: "memory");
    else if (j == 30) asm volatile("s_waitcnt vmcnt(2)" ::: "memory");
    else             asm volatile("s_waitcnt vmcnt(0)" ::: "memory");
    __builtin_amdgcn_sched_barrier(0);
    __builtin_amdgcn_s_barrier();        // K(j+1), V(j) resident for all waves
    f32x16 sna = {}, snb = {};
    __builtin_amdgcn_s_setprio(1);
    if (j < 31) qk(kread, sna, snb);     // QK(j+1) on MFMA pipe
    sm_pv(sca, scb, vread);              // exp/pack in QK's shadow, then PV(j)
    __builtin_amdgcn_s_setprio(0);
    __builtin_amdgcn_sched_barrier(0);
    __builtin_amdgcn_s_barrier();        // reads consumed before next restage
    sca = sna; scb = snb;
  };

#pragma unroll 2
  for (int j = 0; j < 32; ++j) {
    if ((j & 1) == 0) body(j, kb0, kb1, vb0, vb1);
    else              body(j, kb1, kb0, vb1, vb0);
  }

  // epilogue: normalize, transpose via XOR-swizzled LDS (reuse smem), store
  const float inv = 1.0f / otls[0];
  bf16_t* ob = (bf16_t*)(smem + w * 4096);
#pragma unroll
  for (int rg = 0; rg < 4; ++rg) {
    const int d0 = rg * 8 + hi * 4;
    bf16x4 v0, v1;
#pragma unroll
    for (int j = 0; j < 4; ++j) {
      v0[j] = (bf16_t)(ot0[4 * rg + j] * inv);
      v1[j] = (bf16_t)(ot1[4 * rg + j] * inv);
    }
    *(bf16x4*)((char*)ob + ql * 128 + (((d0)      * 2) ^ ((ql & 7) << 4))) = v0;
    *(bf16x4*)((char*)ob + ql * 128 + (((d0 + 32) * 2) ^ ((ql & 7) << 4))) = v1;
  }
  __syncthreads();
#pragma unroll
  for (int i = 0; i < 4; ++i) {
    const int c = i * 64 + l;
    const int qq = c >> 3, ch = c & 7;
    bf16x8 vv = *(const bf16x8*)((char*)ob + qq * 128 + ((ch * 16) ^ ((qq & 7) << 4)));
    *(bf16x8*)(Ao + (size_t)(b * 2048 + q0 + qq) * 1024 + h * 64 + ch * 8) = vv;
  }
}

// ---------------- launcher ----------------

extern "C" void kernel_launch(void* const* d_in, const int* in_sizes, int n_in,
                              void* d_out, int out_size, void* d_ws, size_t ws_size,
                              hipStream_t stream) {
  const float* x    = (const float*)d_in[0];  // [2,2048,1024]
  const float* wqkv = (const float*)d_in[1];  // [1024,3072]
  const float* wo   = (const float*)d_in[2];  // [1024,1024]
  float* out = (float*)d_out;

  char* ws = (char*)d_ws;
  bf16_t* xb    = (bf16_t*)(ws);                        // 8 MB  [4096][1024]
  bf16_t* wqkvT = (bf16_t*)(ws + (size_t)(8u  << 20));  // 6 MB  [3072][1024]
  bf16_t* woT   = (bf16_t*)(ws + (size_t)(14u << 20));  // 2 MB  [1024][1024]
  bf16_t* Qb    = (bf16_t*)(ws + (size_t)(16u << 20));  // 8 MB  [32][2048][64]
  bf16_t* Kb    = (bf16_t*)(ws + (size_t)(24u << 20));  // 8 MB
  bf16_t* Vtb   = (bf16_t*)(ws + (size_t)(32u << 20));  // 8 MB  [32][64][2048] (kv-permuted)
  bf16_t* attn  = (bf16_t*)(ws + (size_t)(40u << 20));  // 8 MB  [4096][1024]

  prep_k<<<8192, 256, 0, stream>>>(x, xb, wqkv, wqkvT, wo, woT);
  gemm_qkv_k<<<dim3(32, 24), 256, 0, stream>>>(xb, wqkvT, Qb, Kb, Vtb);
  attn_k<<<dim3(16, 32), 256, 0, stream>>>(Qb, Kb, Vtb, attn);
  gemm_o_k<<<dim3(32, 8), 256, 0, stream>>>(attn, woT, out);
}